// Round 6
// baseline (2293.857 us; speedup 1.0000x reference)
//
#include <hip/hip_runtime.h>
#include <math.h>

#define NLEVEL 16
#define TSIZE 16384

struct NsParam { int n[NLEVEL]; unsigned densemask; };

// Wave-uniform weight loads through the scalar unit (s_load): cast to the
// constant address space so weights become s_load + v_fmac v,s,v.
typedef const __attribute__((address_space(4))) float* cfp;
__device__ __forceinline__ cfp cc(const float* p) {
    return (cfp)(unsigned long long)p;
}

// Occupancy history:
//  r1: default alloc            -> 196 VGPR, 2 w/SIMD, no spill, 2312 us
//  r2-r4: waves_per_eu hints    -> 64 VGPR, 8 w/SIMD, 3 GB spill, ~1780 us
//  r5: default + chunked        -> 184 VGPR, 2 w/SIMD, no spill, 2018 us
// Peak live pressure in this structure is ~100 regs. amdgpu_num_vgpr(128)
// pins the allocator at exactly the 4-waves/SIMD budget WITHOUT the
// occupancy-boost heuristic that produced the 64-VGPR spill pathology.
__global__ __launch_bounds__(256)
__attribute__((amdgpu_num_vgpr(128)))
void nerf_fused(
    const float* __restrict__ x,
    const float* __restrict__ embed,
    const float* __restrict__ dW0, const float* __restrict__ db0,
    const float* __restrict__ dW1, const float* __restrict__ db1,
    const float* __restrict__ cW0, const float* __restrict__ cb0,
    const float* __restrict__ cW1, const float* __restrict__ cb1,
    const float* __restrict__ cW2, const float* __restrict__ cb2,
    float* __restrict__ out, int B, NsParam ns)
{
    int idx = blockIdx.x * blockDim.x + threadIdx.x;
    if (idx >= B) return;

    cfp DW0 = cc(dW0), DB0 = cc(db0), DW1 = cc(dW1), DB1 = cc(db1);
    cfp CW0 = cc(cW0), CB0 = cc(cb0), CW1 = cc(cW1), CB1 = cc(cb1);
    cfp CW2 = cc(cW2), CB2 = cc(cb2);

    const float* xp = x + (long long)idx * 6;
    float px = xp[0], py = xp[1], pz = xp[2];
    float vx = xp[3], vy = xp[4], vz = xp[5];

    float cx = fminf(fmaxf((px + 5.0f) / 10.0f, 0.0f), 0.999999f);
    float cy = fminf(fmaxf((py + 5.0f) / 10.0f, 0.0f), 0.999999f);
    float cz = fminf(fmaxf((pz + 5.0f) / 10.0f, 0.0f), 0.999999f);

    // ---- Phase A: hashgrid encode -> feats[32] (peak ~60 regs) ----
    float feats[32];
    #pragma unroll
    for (int l = 0; l < NLEVEL; ++l) {
        int n = ns.n[l];
        float fn = (float)n;
        float xl0 = cx * fn, xl1 = cy * fn, xl2 = cz * fn;
        float f0 = floorf(xl0), f1 = floorf(xl1), f2 = floorf(xl2);
        int i0 = (int)f0, i1 = (int)f1, i2 = (int)f2;
        float w0 = xl0 - f0, w1 = xl1 - f1, w2 = xl2 - f2;
        const float* eb = embed + l * (TSIZE * 2);
        int np1 = n + 1;
        bool dense = (ns.densemask >> l) & 1u;

        float2 fe[8];
        #pragma unroll
        for (int c = 0; c < 8; ++c) {
            int o0 = (c >> 2) & 1, o1 = (c >> 1) & 1, o2 = c & 1;
            int ind;
            if (dense) {
                ind = (i0 + o0) * np1 * np1 + (i1 + o1) * np1 + (i2 + o2);
            } else {
                unsigned h = (unsigned)(i0 + o0) * 1u
                           ^ (unsigned)(i1 + o1) * 2654435761u
                           ^ (unsigned)(i2 + o2) * 805459861u;
                ind = (int)(h & (TSIZE - 1));
            }
            fe[c] = *(const float2*)(eb + (long long)ind * 2);
        }
        float a0 = 0.0f, a1 = 0.0f;
        #pragma unroll
        for (int c = 0; c < 8; ++c) {
            int o0 = (c >> 2) & 1, o1 = (c >> 1) & 1, o2 = c & 1;
            float ww = (o0 ? w0 : 1.0f - w0)
                     * (o1 ? w1 : 1.0f - w1)
                     * (o2 ? w2 : 1.0f - w2);
            a0 = fmaf(fe[c].x, ww, a0);
            a1 = fmaf(fe[c].y, ww, a1);
        }
        feats[2 * l]     = a0;
        feats[2 * l + 1] = a1;
    }

    // ---- Phase B: density layers 0+1 fused, h64 chunked 4x16 ----
    float h16[16];
    #pragma unroll
    for (int k = 0; k < 16; ++k) h16[k] = DB1[k];

    #pragma unroll
    for (int c4 = 0; c4 < 4; ++c4) {
        float hc[16];
        #pragma unroll
        for (int j = 0; j < 16; ++j) hc[j] = DB0[c4 * 16 + j];
        #pragma unroll
        for (int i = 0; i < 32; ++i) {
            float a = feats[i];
            cfp wr = DW0 + i * 64 + c4 * 16;
            #pragma unroll
            for (int j = 0; j < 16; ++j) hc[j] = fmaf(a, wr[j], hc[j]);
        }
        #pragma unroll
        for (int j = 0; j < 16; ++j) {
            float a = fmaxf(hc[j], 0.0f);
            cfp wr = DW1 + (c4 * 16 + j) * 16;
            #pragma unroll
            for (int k = 0; k < 16; ++k) h16[k] = fmaf(a, wr[k], h16[k]);
        }
    }

    float density = 1.0f / (1.0f + expf(-h16[0]));

    // ---- color input: [density, relu(h16[1..15]), view] (19) ----
    float cin[19];
    cin[0] = density;
    #pragma unroll
    for (int k = 1; k < 16; ++k) cin[k] = fmaxf(h16[k], 0.0f);
    cin[16] = vx; cin[17] = vy; cin[18] = vz;

    // ---- color layer 0: 19 -> 64, relu (peak ~95 regs) ----
    float c1[64];
    #pragma unroll
    for (int j = 0; j < 64; ++j) c1[j] = CB0[j];
    #pragma unroll
    for (int i = 0; i < 19; ++i) {
        cfp wr = CW0 + i * 64;
        float a = cin[i];
        #pragma unroll
        for (int j = 0; j < 64; ++j) c1[j] = fmaf(a, wr[j], c1[j]);
    }
    #pragma unroll
    for (int j = 0; j < 64; ++j) c1[j] = fmaxf(c1[j], 0.0f);

    // ---- color layers 1+2 fused, c2 chunked 4x16 (peak ~90 regs) ----
    float col0 = CB2[0], col1 = CB2[1], col2 = CB2[2];
    #pragma unroll
    for (int k = 0; k < 4; ++k) {
        float c2k[16];
        #pragma unroll
        for (int j = 0; j < 16; ++j) c2k[j] = CB1[k * 16 + j];
        #pragma unroll
        for (int i = 0; i < 64; ++i) {
            float a = c1[i];
            cfp wr = CW1 + i * 64 + k * 16;
            #pragma unroll
            for (int j = 0; j < 16; ++j) c2k[j] = fmaf(a, wr[j], c2k[j]);
        }
        #pragma unroll
        for (int j = 0; j < 16; ++j) {
            float a = fmaxf(c2k[j], 0.0f);
            int jj = k * 16 + j;
            col0 = fmaf(a, CW2[jj * 3 + 0], col0);
            col1 = fmaf(a, CW2[jj * 3 + 1], col1);
            col2 = fmaf(a, CW2[jj * 3 + 2], col2);
        }
    }

    float4 o;
    o.x = density;
    o.y = 1.0f / (1.0f + expf(-col0));
    o.z = 1.0f / (1.0f + expf(-col1));
    o.w = 1.0f / (1.0f + expf(-col2));
    *(float4*)(out + (long long)idx * 4) = o;
}

extern "C" void kernel_launch(void* const* d_in, const int* in_sizes, int n_in,
                              void* d_out, int out_size, void* d_ws, size_t ws_size,
                              hipStream_t stream) {
    const float* x    = (const float*)d_in[0];
    const float* embed= (const float*)d_in[1];
    const float* dW0  = (const float*)d_in[2];
    const float* db0  = (const float*)d_in[3];
    const float* dW1  = (const float*)d_in[4];
    const float* db1  = (const float*)d_in[5];
    const float* cW0  = (const float*)d_in[6];
    const float* cb0  = (const float*)d_in[7];
    const float* cW1  = (const float*)d_in[8];
    const float* cb1  = (const float*)d_in[9];
    const float* cW2  = (const float*)d_in[10];
    const float* cb2  = (const float*)d_in[11];
    float* out = (float*)d_out;

    int B = in_sizes[0] / 6;

    // Replicate numpy's NS computation bit-for-bit (same libm on this host):
    // B_GROWTH = exp((log(512)-log(16))/15); NS[l] = int(16 * B_GROWTH**l)
    NsParam ns;
    double g = exp((log(512.0) - log(16.0)) / 15.0);
    ns.densemask = 0;
    for (int i = 0; i < NLEVEL; ++i) {
        ns.n[i] = (int)(16.0 * pow(g, (double)i));
        long long np1 = ns.n[i] + 1;
        if (np1 * np1 * np1 <= TSIZE) ns.densemask |= (1u << i);
    }

    int block = 256;
    int grid = (B + block - 1) / block;
    nerf_fused<<<grid, block, 0, stream>>>(x, embed,
        dW0, db0, dW1, db1, cW0, cb0, cW1, cb1, cW2, cb2,
        out, B, ns);
}

// Round 7
// 1046.196 us; speedup vs baseline: 2.1926x; 2.1926x over previous
//
#include <hip/hip_runtime.h>
#include <math.h>

#define NLEVEL 16
#define TSIZE 16384

using short8 = __attribute__((ext_vector_type(8))) short;
using f32x4  = __attribute__((ext_vector_type(4))) float;

struct NsParam { int n[NLEVEL]; unsigned densemask; };

union Frag { short8 v; int i[4]; };

// round-to-nearest-even f32 -> bf16, packed pair (lo in low 16, hi in high 16)
__device__ __forceinline__ int pack_bf2(float lo, float hi) {
    unsigned a = __float_as_uint(lo);
    unsigned b = __float_as_uint(hi);
    a = (a + 0x7fffu + ((a >> 16) & 1u)) >> 16;
    b = (b + 0x7fffu + ((b >> 16) & 1u)) & 0xffff0000u;
    return (int)(a | b);
}

// A-fragment for mfma_f32_16x16x32_bf16 of W^T, W row-major [K][N] fp32.
// Lane holds A[m=out][k=k0+j], j=0..7 ascending (pairs packed lo/hi).
__device__ __forceinline__ Frag load_wfrag(const float* __restrict__ W, int ldn,
                                           int k0, int out, int kmax, int omax) {
    Frag f;
    #pragma unroll
    for (int p = 0; p < 4; ++p) {
        int ka = k0 + 2 * p, kb = k0 + 2 * p + 1;
        float lo = (ka < kmax && out < omax) ? W[ka * ldn + out] : 0.0f;
        float hi = (kb < kmax && out < omax) ? W[kb * ldn + out] : 0.0f;
        f.i[p] = pack_bf2(lo, hi);
    }
    return f;
}

// C-layout (col=lane&15=pt, row=out=16t+4q+reg) -> B-frags for next layer
// (B[k=32f+8q+j][n=pt]). Movement stays within the 4 lanes sharing lane&15:
// src quad = 2*(q&1)+(p>>1), src tile t = 2f+(q>>1), src regs = (2p%4, +1).
// pk[t][h] = packed activated pair (reg 2h, 2h+1) of tile t.
__device__ __forceinline__ void trans64(const int pk[4][2], int lane,
                                        Frag& b0, Frag& b1) {
    int pt = lane & 15, q = lane >> 4;
    int qlo = q & 1, qhi = q >> 1;
    #pragma unroll
    for (int p = 0; p < 4; ++p) {
        int src = pt + 16 * (2 * qlo + (p >> 1));
        int h = p & 1;
        int v00 = __shfl(pk[0][h], src, 64);
        int v01 = __shfl(pk[1][h], src, 64);
        int v10 = __shfl(pk[2][h], src, 64);
        int v11 = __shfl(pk[3][h], src, 64);
        b0.i[p] = qhi ? v01 : v00;
        b1.i[p] = qhi ? v11 : v10;
    }
}

__device__ __forceinline__ f32x4 mfma16(const Frag& a, const Frag& b, f32x4 c) {
    return __builtin_amdgcn_mfma_f32_16x16x32_bf16(a.v, b.v, c, 0, 0, 0);
}

__device__ __forceinline__ float sigmoidf(float x) {
    return 1.0f / (1.0f + expf(-x));
}

// One wave processes 16 points. Lane (pt=lane&15, q=lane>>4).
// Encode: lane computes levels 4q..4q+3 -> exactly its feats B-fragment.
// All layers as C[out][pt] = W^T @ act^T via 16x16x32 bf16 MFMA.
__global__ __launch_bounds__(256) void nerf_mfma(
    const float* __restrict__ x,
    const float* __restrict__ embed,
    const float* __restrict__ dW0, const float* __restrict__ db0,
    const float* __restrict__ dW1, const float* __restrict__ db1,
    const float* __restrict__ cW0, const float* __restrict__ cb0,
    const float* __restrict__ cW1, const float* __restrict__ cb1,
    const float* __restrict__ cW2, const float* __restrict__ cb2,
    float* __restrict__ out, int B, NsParam ns)
{
    const int lane = threadIdx.x & 63;
    const int pt = lane & 15;
    const int q  = lane >> 4;
    const int wavesPerBlock = blockDim.x >> 6;
    const int waveId = blockIdx.x * wavesPerBlock + (threadIdx.x >> 6);
    const int waveStride = gridDim.x * wavesPerBlock;
    const int numTiles = B >> 4;
    const int k0 = 8 * q;

    // ---- resident weight A-fragments (loaded once per wave, ~80 VGPRs) ----
    Frag wdW0[4], wdW1[2], wcW0[4], wcW1[4][2], wcW2[2];
    #pragma unroll
    for (int t = 0; t < 4; ++t) wdW0[t] = load_wfrag(dW0, 64, k0, 16*t + pt, 32, 64);
    wdW1[0] = load_wfrag(dW1, 16, k0,      pt, 64, 16);
    wdW1[1] = load_wfrag(dW1, 16, 32 + k0, pt, 64, 16);
    #pragma unroll
    for (int t = 0; t < 4; ++t) wcW0[t] = load_wfrag(cW0, 64, k0, 16*t + pt, 19, 64);
    #pragma unroll
    for (int t = 0; t < 4; ++t) {
        wcW1[t][0] = load_wfrag(cW1, 64, k0,      16*t + pt, 64, 64);
        wcW1[t][1] = load_wfrag(cW1, 64, 32 + k0, 16*t + pt, 64, 64);
    }
    wcW2[0] = load_wfrag(cW2, 3, k0,      pt, 64, 3);
    wcW2[1] = load_wfrag(cW2, 3, 32 + k0, pt, 64, 3);

    for (int tile = waveId; tile < numTiles; tile += waveStride) {
        const int ptg = tile * 16 + pt;
        const float* xp = x + (size_t)ptg * 6;
        float px = xp[0], py = xp[1], pz = xp[2];
        float vx = xp[3], vy = xp[4], vz = xp[5];

        float cx = fminf(fmaxf((px + 5.0f) / 10.0f, 0.0f), 0.999999f);
        float cy = fminf(fmaxf((py + 5.0f) / 10.0f, 0.0f), 0.999999f);
        float cz = fminf(fmaxf((pz + 5.0f) / 10.0f, 0.0f), 0.999999f);

        // ---- encode: 4 levels per lane -> feats B-frag (k=8q+2d, 8q+2d+1) ----
        Frag bfeat;
        #pragma unroll
        for (int d = 0; d < 4; ++d) {
            int nA = ns.n[d], nB = ns.n[4 + d], nC = ns.n[8 + d], nD = ns.n[12 + d];
            int n = (q & 2) ? ((q & 1) ? nD : nC) : ((q & 1) ? nB : nA);
            int l = 4 * q + d;
            bool dense = (ns.densemask >> l) & 1u;
            float fn = (float)n;
            float xl0 = cx * fn, xl1 = cy * fn, xl2 = cz * fn;
            float f0 = floorf(xl0), f1 = floorf(xl1), f2 = floorf(xl2);
            int i0 = (int)f0, i1 = (int)f1, i2 = (int)f2;
            float w0 = xl0 - f0, w1 = xl1 - f1, w2 = xl2 - f2;
            int np1 = n + 1;
            const float* eb = embed + (size_t)l * (TSIZE * 2);

            float2 fe[8];
            #pragma unroll
            for (int c = 0; c < 8; ++c) {
                int o0 = (c >> 2) & 1, o1 = (c >> 1) & 1, o2 = c & 1;
                int dIdx = (i0 + o0) * np1 * np1 + (i1 + o1) * np1 + (i2 + o2);
                unsigned h = (unsigned)(i0 + o0) * 1u
                           ^ (unsigned)(i1 + o1) * 2654435761u
                           ^ (unsigned)(i2 + o2) * 805459861u;
                int hIdx = (int)(h & (TSIZE - 1));
                int ind = dense ? dIdx : hIdx;
                fe[c] = *(const float2*)(eb + (size_t)ind * 2);
            }
            float a0 = 0.0f, a1 = 0.0f;
            #pragma unroll
            for (int c = 0; c < 8; ++c) {
                int o0 = (c >> 2) & 1, o1 = (c >> 1) & 1, o2 = c & 1;
                float ww = (o0 ? w0 : 1.0f - w0)
                         * (o1 ? w1 : 1.0f - w1)
                         * (o2 ? w2 : 1.0f - w2);
                a0 = fmaf(fe[c].x, ww, a0);
                a1 = fmaf(fe[c].y, ww, a1);
            }
            bfeat.i[d] = pack_bf2(a0, a1);
        }

        // ---- L0: h64^T = dW0^T @ feats^T  (4 out-tiles, K=32) ----
        f32x4 acc[4];
        #pragma unroll
        for (int t = 0; t < 4; ++t) {
            acc[t] = *(const f32x4*)(db0 + 16 * t + 4 * q);
            acc[t] = mfma16(wdW0[t], bfeat, acc[t]);
        }
        int pk[4][2];
        #pragma unroll
        for (int t = 0; t < 4; ++t) {
            pk[t][0] = pack_bf2(fmaxf(acc[t][0], 0.0f), fmaxf(acc[t][1], 0.0f));
            pk[t][1] = pack_bf2(fmaxf(acc[t][2], 0.0f), fmaxf(acc[t][3], 0.0f));
        }
        Frag bh0, bh1;
        trans64(pk, lane, bh0, bh1);

        // ---- L1: h16^T = dW1^T @ relu(h64)^T  (1 tile, K=64) ----
        f32x4 h = *(const f32x4*)(db1 + 4 * q);
        h = mfma16(wdW1[0], bh0, h);
        h = mfma16(wdW1[1], bh1, h);

        float dens = sigmoidf(h[0]);                   // valid where q==0 (out 0)
        float a0v = (q == 0) ? dens : fmaxf(h[0], 0.0f);
        int pkh0 = pack_bf2(a0v, fmaxf(h[1], 0.0f));
        int pkh1 = pack_bf2(fmaxf(h[2], 0.0f), fmaxf(h[3], 0.0f));

        // ---- cin B-frag: k0..15 = act(h16), k16..18 = view, k19..31 = 0 ----
        Frag bcin;
        {
            int qlo = q & 1;
            #pragma unroll
            for (int p = 0; p < 4; ++p) {
                int src = pt + 16 * (2 * qlo + (p >> 1));
                bcin.i[p] = __shfl((p & 1) ? pkh1 : pkh0, src, 64);
            }
            if (q >= 2) {
                bcin.i[0] = (q == 2) ? pack_bf2(vx, vy) : 0;
                bcin.i[1] = (q == 2) ? pack_bf2(vz, 0.0f) : 0;
                bcin.i[2] = 0;
                bcin.i[3] = 0;
            }
        }

        // ---- L2: c1^T = cW0^T @ cin^T  (4 out-tiles, K=19 pad 32) ----
        #pragma unroll
        for (int t = 0; t < 4; ++t) {
            acc[t] = *(const f32x4*)(cb0 + 16 * t + 4 * q);
            acc[t] = mfma16(wcW0[t], bcin, acc[t]);
        }
        #pragma unroll
        for (int t = 0; t < 4; ++t) {
            pk[t][0] = pack_bf2(fmaxf(acc[t][0], 0.0f), fmaxf(acc[t][1], 0.0f));
            pk[t][1] = pack_bf2(fmaxf(acc[t][2], 0.0f), fmaxf(acc[t][3], 0.0f));
        }
        Frag bc0, bc1;
        trans64(pk, lane, bc0, bc1);

        // ---- L3: c2^T = cW1^T @ relu(c1)^T  (4 out-tiles, K=64) ----
        #pragma unroll
        for (int t = 0; t < 4; ++t) {
            acc[t] = *(const f32x4*)(cb1 + 16 * t + 4 * q);
            acc[t] = mfma16(wcW1[t][0], bc0, acc[t]);
            acc[t] = mfma16(wcW1[t][1], bc1, acc[t]);
        }
        #pragma unroll
        for (int t = 0; t < 4; ++t) {
            pk[t][0] = pack_bf2(fmaxf(acc[t][0], 0.0f), fmaxf(acc[t][1], 0.0f));
            pk[t][1] = pack_bf2(fmaxf(acc[t][2], 0.0f), fmaxf(acc[t][3], 0.0f));
        }
        Frag bd0, bd1;
        trans64(pk, lane, bd0, bd1);

        // ---- L4: col^T = cW2^T @ relu(c2)^T  (outs 0..2, K=64) ----
        f32x4 fo = {0.0f, 0.0f, 0.0f, 0.0f};
        if (q == 0) { fo[0] = cb2[0]; fo[1] = cb2[1]; fo[2] = cb2[2]; }
        fo = mfma16(wcW2[0], bd0, fo);
        fo = mfma16(wcW2[1], bd1, fo);

        if (q == 0) {
            f32x4 o;
            o[0] = dens;
            o[1] = sigmoidf(fo[0]);
            o[2] = sigmoidf(fo[1]);
            o[3] = sigmoidf(fo[2]);
            *(f32x4*)(out + (size_t)ptg * 4) = o;
        }
    }
}

extern "C" void kernel_launch(void* const* d_in, const int* in_sizes, int n_in,
                              void* d_out, int out_size, void* d_ws, size_t ws_size,
                              hipStream_t stream) {
    const float* x    = (const float*)d_in[0];
    const float* embed= (const float*)d_in[1];
    const float* dW0  = (const float*)d_in[2];
    const float* db0  = (const float*)d_in[3];
    const float* dW1  = (const float*)d_in[4];
    const float* db1  = (const float*)d_in[5];
    const float* cW0  = (const float*)d_in[6];
    const float* cb0  = (const float*)d_in[7];
    const float* cW1  = (const float*)d_in[8];
    const float* cb1  = (const float*)d_in[9];
    const float* cW2  = (const float*)d_in[10];
    const float* cb2  = (const float*)d_in[11];
    float* out = (float*)d_out;

    int B = in_sizes[0] / 6;

    // Replicate numpy's NS computation bit-for-bit (same libm on this host).
    NsParam ns;
    double g = exp((log(512.0) - log(16.0)) / 15.0);
    ns.densemask = 0;
    for (int i = 0; i < NLEVEL; ++i) {
        ns.n[i] = (int)(16.0 * pow(g, (double)i));
        long long np1 = ns.n[i] + 1;
        if (np1 * np1 * np1 <= TSIZE) ns.densemask |= (1u << i);
    }

    // 16 points/wave; grid-stride over tiles. 2048 blocks x 4 waves = 8192
    // waves -> 16 tiles/wave at B=2M (amortizes the one-time weight-frag load).
    int block = 256;
    int grid = 2048;
    nerf_mfma<<<grid, block, 0, stream>>>(x, embed,
        dW0, db0, dW1, db1, cW0, cb0, cW1, cb1, cW2, cb2,
        out, B, ns);
}

// Round 8
// 1015.821 us; speedup vs baseline: 2.2581x; 1.0299x over previous
//
#include <hip/hip_runtime.h>
#include <math.h>

#define NLEVEL 16
#define TSIZE 16384

using half4 = __attribute__((ext_vector_type(4))) _Float16;
using f32x4 = __attribute__((ext_vector_type(4))) float;

struct NsParam { int n[NLEVEL]; unsigned densemask; };

union Frag { half4 v; int i[2]; };

// Block loop-invariant code motion from hoisting per-tile bias loads into
// 55 permanently-live VGPRs: make the pointer "new" every iteration.
__device__ __forceinline__ void opaque(const float*& p) {
    asm("" : "+v"(p));
}

// A-fragment for mfma_f32_16x16x16f16 of W^T (W row-major [K][N] fp32):
// lane (pt=lane&15, q=lane>>4) holds A[m=out][k=k0+4q+j], j=0..3.
__device__ __forceinline__ Frag load_wfrag(const float* __restrict__ W, int ldn,
                                           int k0, int q, int out,
                                           int kmax, int omax) {
    Frag f;
    #pragma unroll
    for (int j = 0; j < 4; ++j) {
        int k = k0 + 4 * q + j;
        float v = (k < kmax && out < omax) ? W[k * ldn + out] : 0.0f;
        f.v[j] = (_Float16)v;
    }
    return f;
}

__device__ __forceinline__ f32x4 mfma16(const Frag& a, const Frag& b, f32x4 c) {
    return __builtin_amdgcn_mfma_f32_16x16x16f16(a.v, b.v, c, 0, 0, 0);
}

// relu + cvt: C-tile f32x4 -> B-fragment half4 (layouts match for K=16!)
__device__ __forceinline__ Frag actpack(f32x4 a) {
    Frag f;
    #pragma unroll
    for (int j = 0; j < 4; ++j) f.v[j] = (_Float16)fmaxf(a[j], 0.0f);
    return f;
}

__device__ __forceinline__ float sigmoidf(float x) {
    return 1.0f / (1.0f + expf(-x));
}

// q-select among 4 values (q = lane>>4)
__device__ __forceinline__ int qsel(int q, int a, int b, int c, int d) {
    return (q & 2) ? ((q & 1) ? d : c) : ((q & 1) ? b : a);
}

// One wave = 16 points. Lane (pt, q). All layers via 16x16x16 f16 MFMA;
// K=16 makes C-layout == B-layout so layer chaining needs NO cross-lane ops.
__global__ __launch_bounds__(256) void nerf_mfma(
    const float* __restrict__ x,
    const float* __restrict__ embed,
    const float* __restrict__ dW0, const float* __restrict__ db0,
    const float* __restrict__ dW1, const float* __restrict__ db1,
    const float* __restrict__ cW0, const float* __restrict__ cb0,
    const float* __restrict__ cW1, const float* __restrict__ cb1,
    const float* __restrict__ cW2, const float* __restrict__ cb2,
    float* __restrict__ out, int B, NsParam ns)
{
    const int lane = threadIdx.x & 63;
    const int pt = lane & 15;
    const int q  = lane >> 4;
    const int wavesPerBlock = blockDim.x >> 6;
    const int waveId = blockIdx.x * wavesPerBlock + (threadIdx.x >> 6);
    const int waveStride = gridDim.x * wavesPerBlock;
    const int numTiles = B >> 4;

    // ---- resident weight A-fragments (80 VGPRs, loaded once) ----
    // chunk c covers k = 16c + 4q + j.
    Frag wdW0[4][2], wdW1[4], wcW0[4][2], wcW1[4][4], wcW2[4];
    #pragma unroll
    for (int t = 0; t < 4; ++t)
        #pragma unroll
        for (int c = 0; c < 2; ++c)
            wdW0[t][c] = load_wfrag(dW0, 64, 16 * c, q, 16 * t + pt, 32, 64);
    #pragma unroll
    for (int c = 0; c < 4; ++c)
        wdW1[c] = load_wfrag(dW1, 16, 16 * c, q, pt, 64, 16);
    #pragma unroll
    for (int t = 0; t < 4; ++t)
        #pragma unroll
        for (int c = 0; c < 2; ++c)
            wcW0[t][c] = load_wfrag(cW0, 64, 16 * c, q, 16 * t + pt, 19, 64);
    #pragma unroll
    for (int t = 0; t < 4; ++t)
        #pragma unroll
        for (int c = 0; c < 4; ++c)
            wcW1[t][c] = load_wfrag(cW1, 64, 16 * c, q, 16 * t + pt, 64, 64);
    #pragma unroll
    for (int c = 0; c < 4; ++c)
        wcW2[c] = load_wfrag(cW2, 3, 16 * c, q, pt, 64, 3);

    // ---- per-lane encode level state (fixed across tiles) ----
    // This lane computes levels {2q, 2q+1, 8+2q, 9+2q} = d 0..3.
    float fn_[4];
    const float* eb_[4];
    int np1_[4], np1sq_[4];
    bool dense_[4];
    #pragma unroll
    for (int d = 0; d < 4; ++d) {
        int base = (d < 2) ? (d) : (8 + (d - 2));   // level = base + 2q
        int lvl = base + 2 * q;
        int n = qsel(q, ns.n[base], ns.n[base + 2], ns.n[base + 4], ns.n[base + 6]);
        fn_[d] = (float)n;
        np1_[d] = n + 1;
        np1sq_[d] = (n + 1) * (n + 1);
        dense_[d] = (ns.densemask >> lvl) & 1u;
        eb_[d] = embed + (size_t)lvl * (TSIZE * 2);
    }

    for (int tile = waveId; tile < numTiles; tile += waveStride) {
        const int ptg = tile * 16 + pt;
        const float* xp = x + (size_t)ptg * 6;
        float2 x01 = *(const float2*)(xp);
        float2 x23 = *(const float2*)(xp + 2);
        float2 x45 = *(const float2*)(xp + 4);
        float px = x01.x, py = x01.y, pz = x23.x;
        float vx = x23.y, vy = x45.x, vz = x45.y;

        float cx = fminf(fmaxf((px + 5.0f) / 10.0f, 0.0f), 0.999999f);
        float cy = fminf(fmaxf((py + 5.0f) / 10.0f, 0.0f), 0.999999f);
        float cz = fminf(fmaxf((pz + 5.0f) / 10.0f, 0.0f), 0.999999f);

        // ---- encode: 4 levels/lane -> B-frags bf0 (k=4q+j), bf1 (k=16+4q+j) ----
        Frag bf0, bf1;
        #pragma unroll
        for (int d = 0; d < 4; ++d) {
            float fn = fn_[d];
            float xl0 = cx * fn, xl1 = cy * fn, xl2 = cz * fn;
            float f0 = floorf(xl0), f1 = floorf(xl1), f2 = floorf(xl2);
            int i0 = (int)f0, i1 = (int)f1, i2 = (int)f2;
            float w0 = xl0 - f0, w1 = xl1 - f1, w2 = xl2 - f2;

            unsigned hx0 = (unsigned)i0, hx1 = hx0 + 1u;
            unsigned hy0 = (unsigned)i1 * 2654435761u, hy1 = hy0 + 2654435761u;
            unsigned hz0 = (unsigned)i2 * 805459861u,  hz1 = hz0 + 805459861u;
            int dx0 = 0, dx1 = 0, dy0 = 0, dy1 = 0;
            if (d < 2) {  // only levels 0,1 can be dense
                dx0 = i0 * np1sq_[d]; dx1 = dx0 + np1sq_[d];
                dy0 = i1 * np1_[d];   dy1 = dy0 + np1_[d];
            }

            float2 fe[8];
            #pragma unroll
            for (int c = 0; c < 8; ++c) {
                int o0 = (c >> 2) & 1, o1 = (c >> 1) & 1, o2 = c & 1;
                unsigned h = (o0 ? hx1 : hx0) ^ (o1 ? hy1 : hy0) ^ (o2 ? hz1 : hz0);
                int ind = (int)(h & (TSIZE - 1));
                if (d < 2) {
                    int di = (o0 ? dx1 : dx0) + (o1 ? dy1 : dy0) + i2 + o2;
                    ind = dense_[d] ? di : ind;
                }
                fe[c] = *(const float2*)(eb_[d] + (size_t)ind * 2);
            }
            float u0 = 1.0f - w0, u1 = 1.0f - w1, u2 = 1.0f - w2;
            float wxy[4] = { u0 * u1, u0 * w1, w0 * u1, w0 * w1 };
            float a0 = 0.0f, a1 = 0.0f;
            #pragma unroll
            for (int c = 0; c < 8; ++c) {
                float ww = wxy[c >> 1] * ((c & 1) ? w2 : u2);
                a0 = fmaf(fe[c].x, ww, a0);
                a1 = fmaf(fe[c].y, ww, a1);
            }
            if (d == 0)      { bf0.v[0] = (_Float16)a0; bf0.v[1] = (_Float16)a1; }
            else if (d == 1) { bf0.v[2] = (_Float16)a0; bf0.v[3] = (_Float16)a1; }
            else if (d == 2) { bf1.v[0] = (_Float16)a0; bf1.v[1] = (_Float16)a1; }
            else             { bf1.v[2] = (_Float16)a0; bf1.v[3] = (_Float16)a1; }
        }

        // per-iteration opaque bias pointers (defeats LICM register hoisting)
        const float* db0o = db0; const float* db1o = db1;
        const float* cb0o = cb0; const float* cb1o = cb1;
        const float* cb2o = cb2;
        opaque(db0o); opaque(db1o); opaque(cb0o); opaque(cb1o); opaque(cb2o);

        // ---- L0: h64 = dW0^T @ feats (4 out-tiles, K=32) ----
        f32x4 acc[4];
        #pragma unroll
        for (int t = 0; t < 4; ++t) {
            acc[t] = *(const f32x4*)(db0o + 16 * t + 4 * q);
            acc[t] = mfma16(wdW0[t][0], bf0, acc[t]);
            acc[t] = mfma16(wdW0[t][1], bf1, acc[t]);
        }
        Frag bh[4];
        #pragma unroll
        for (int c = 0; c < 4; ++c) bh[c] = actpack(acc[c]);

        // ---- L1: h16 = dW1^T @ relu(h64) (1 tile, K=64) ----
        f32x4 h = *(const f32x4*)(db1o + 4 * q);
        #pragma unroll
        for (int c = 0; c < 4; ++c) h = mfma16(wdW1[c], bh[c], h);

        float dens = sigmoidf(h[0]);            // row 0 lives at q==0, reg 0
        Frag bcin0, bcin1;
        {
            float a0v = (q == 0) ? dens : fmaxf(h[0], 0.0f);
            bcin0.v[0] = (_Float16)a0v;
            bcin0.v[1] = (_Float16)fmaxf(h[1], 0.0f);
            bcin0.v[2] = (_Float16)fmaxf(h[2], 0.0f);
            bcin0.v[3] = (_Float16)fmaxf(h[3], 0.0f);
            // k=16+4q+j: q==0 holds k16..19 = (vx,vy,vz,0) of its own point
            bcin1.v[0] = (_Float16)((q == 0) ? vx : 0.0f);
            bcin1.v[1] = (_Float16)((q == 0) ? vy : 0.0f);
            bcin1.v[2] = (_Float16)((q == 0) ? vz : 0.0f);
            bcin1.v[3] = (_Float16)0.0f;
        }

        // ---- L2: c1 = cW0^T @ cin (4 out-tiles, K=19 padded to 32) ----
        #pragma unroll
        for (int t = 0; t < 4; ++t) {
            acc[t] = *(const f32x4*)(cb0o + 16 * t + 4 * q);
            acc[t] = mfma16(wcW0[t][0], bcin0, acc[t]);
            acc[t] = mfma16(wcW0[t][1], bcin1, acc[t]);
        }
        Frag bc[4];
        #pragma unroll
        for (int c = 0; c < 4; ++c) bc[c] = actpack(acc[c]);

        // ---- L3: c2 = cW1^T @ relu(c1) (4 out-tiles, K=64) ----
        #pragma unroll
        for (int t = 0; t < 4; ++t) {
            acc[t] = *(const f32x4*)(cb1o + 16 * t + 4 * q);
            #pragma unroll
            for (int c = 0; c < 4; ++c) acc[t] = mfma16(wcW1[t][c], bc[c], acc[t]);
        }
        Frag bd[4];
        #pragma unroll
        for (int c = 0; c < 4; ++c) bd[c] = actpack(acc[c]);

        // ---- L4: col = cW2^T @ relu(c2) (rows 0..2, K=64) ----
        float b0 = cb2o[0], b1 = cb2o[1], b2 = cb2o[2];
        f32x4 fo;
        fo[0] = (q == 0) ? b0 : 0.0f;
        fo[1] = (q == 0) ? b1 : 0.0f;
        fo[2] = (q == 0) ? b2 : 0.0f;
        fo[3] = 0.0f;
        #pragma unroll
        for (int c = 0; c < 4; ++c) fo = mfma16(wcW2[c], bd[c], fo);

        if (q == 0) {
            f32x4 o;
            o[0] = dens;
            o[1] = sigmoidf(fo[0]);
            o[2] = sigmoidf(fo[1]);
            o[3] = sigmoidf(fo[2]);
            *(f32x4*)(out + (size_t)ptg * 4) = o;
        }
    }
}

extern "C" void kernel_launch(void* const* d_in, const int* in_sizes, int n_in,
                              void* d_out, int out_size, void* d_ws, size_t ws_size,
                              hipStream_t stream) {
    const float* x    = (const float*)d_in[0];
    const float* embed= (const float*)d_in[1];
    const float* dW0  = (const float*)d_in[2];
    const float* db0  = (const float*)d_in[3];
    const float* dW1  = (const float*)d_in[4];
    const float* db1  = (const float*)d_in[5];
    const float* cW0  = (const float*)d_in[6];
    const float* cb0  = (const float*)d_in[7];
    const float* cW1  = (const float*)d_in[8];
    const float* cb1  = (const float*)d_in[9];
    const float* cW2  = (const float*)d_in[10];
    const float* cb2  = (const float*)d_in[11];
    float* out = (float*)d_out;

    int B = in_sizes[0] / 6;

    // Replicate numpy's NS computation bit-for-bit (same libm on this host).
    NsParam ns;
    double g = exp((log(512.0) - log(16.0)) / 15.0);
    ns.densemask = 0;
    for (int i = 0; i < NLEVEL; ++i) {
        ns.n[i] = (int)(16.0 * pow(g, (double)i));
        long long np1 = ns.n[i] + 1;
        if (np1 * np1 * np1 <= TSIZE) ns.densemask |= (1u << i);
    }

    int block = 256;
    int grid = 2048;   // 8192 waves, 16 tiles/wave at B=2M
    nerf_mfma<<<grid, block, 0, stream>>>(x, embed,
        dW0, db0, dW1, db1, cW0, cb0, cW1, cb1, cW2, cb2,
        out, B, ns);
}